// Round 6
// baseline (719.759 us; speedup 1.0000x reference)
//
#include <hip/hip_runtime.h>
#include <math.h>

#define NN 20000
#define NE 200000
#define HH 512

typedef __attribute__((ext_vector_type(8))) short short8v;
typedef __attribute__((ext_vector_type(4))) float f32x4;

__device__ inline short f2bf(float f) {
    union { float f; unsigned u; } v; v.f = f;
    unsigned r = (v.u + 0x7fffu + ((v.u >> 16) & 1u)) >> 16;
    return (short)r;
}
__device__ inline float bf2f(short s) {
    union { unsigned u; float f; } v;
    v.u = ((unsigned)(unsigned short)s) << 16;
    return v.f;
}

// direct global->LDS DMA, 16B per lane; lds dest must be wave-uniform base
__device__ inline void gload_lds16(const void* g, void* l) {
    __builtin_amdgcn_global_load_lds(
        (const __attribute__((address_space(1))) void*)g,
        (__attribute__((address_space(3))) void*)l, 16, 0, 0);
}

// ---------------- fp32 -> bf16 bulk convert (8 elems/thread) ----------------
__global__ __launch_bounds__(256)
void f2b_kernel(const float* __restrict__ src, short* __restrict__ dst, int n8)
{
    int i = blockIdx.x * 256 + threadIdx.x;
    if (i >= n8) return;
    const float4* p = (const float4*)src + (size_t)i * 2;
    float4 a = p[0], b = p[1];
    short8v s;
    s[0] = f2bf(a.x); s[1] = f2bf(a.y); s[2] = f2bf(a.z); s[3] = f2bf(a.w);
    s[4] = f2bf(b.x); s[5] = f2bf(b.y); s[6] = f2bf(b.z); s[7] = f2bf(b.w);
    ((short8v*)dst)[i] = s;
}

// ---------------- weight transpose + bf16 convert: dst[n][k] = src[k][n] ----
__global__ __launch_bounds__(256)
void wtr_kernel(const float* __restrict__ src, short* __restrict__ dst,
                int K, int Ncols)
{
    __shared__ float t[32][33];
    int bx = blockIdx.x * 32;
    int by = blockIdx.y * 32;
    int tx = threadIdx.x, ty = threadIdx.y;
    for (int i = ty; i < 32; i += 8)
        t[i][tx] = src[(size_t)(by + i) * Ncols + bx + tx];
    __syncthreads();
    for (int i = ty; i < 32; i += 8)
        dst[(size_t)(bx + i) * K + by + tx] = f2bf(t[tx][i]);
}

// ---------------- MFMA GEMM: out[M,512] = X[M,K](bf16) @ WT[512,K](bf16)^T + b
// 128x128 tile, BK=32, 4 waves (2x2), wave 64x64 (4x4 frags of 16x16x32).
__global__ __launch_bounds__(256)
void mfma_lin(const short* __restrict__ X, const short* __restrict__ WT,
              const float* __restrict__ bias, float* __restrict__ outF,
              short* __restrict__ outB, int M, int K)
{
    __shared__ short8v As[2][512];   // [row 0..127][chunk-slot 0..3]
    __shared__ short8v Bs[2][512];

    const int tid = threadIdx.x;
    const int lane = tid & 63;
    const int w = tid >> 6;

    const int nby = (M + 127) >> 7;
    const int nwg = nby << 2;
    const int q = nwg >> 3, r = nwg & 7;
    int id = blockIdx.x;
    int xcd = id & 7, wi = id >> 3;
    int wgid = (xcd < r ? xcd * (q + 1) : r * (q + 1) + (xcd - r) * q) + wi;
    const int col0 = (wgid & 3) * 128;
    const int row0 = (wgid >> 2) * 128;

    const int wr = (w >> 1) * 64;
    const int wc = (w & 1) * 64;

    int sp0 = w * 128 + lane;
    int sp1 = sp0 + 64;
    int r0_ = sp0 >> 2, r1_ = sp1 >> 2;
    int c0_ = (sp0 & 3) ^ ((r0_ >> 1) & 3);
    int c1_ = (sp1 & 3) ^ ((r1_ >> 1) & 3);
    int ga0 = row0 + r0_; if (ga0 >= M) ga0 = M - 1;
    int ga1 = row0 + r1_; if (ga1 >= M) ga1 = M - 1;
    const short* ag0 = X + (size_t)ga0 * K + c0_ * 8;
    const short* ag1 = X + (size_t)ga1 * K + c1_ * 8;
    const short* bg0 = WT + (size_t)(col0 + r0_) * K + c0_ * 8;
    const short* bg1 = WT + (size_t)(col0 + r1_) * K + c1_ * 8;

    int ar[4], br[4];
#pragma unroll
    for (int i = 0; i < 4; ++i) {
        int rr = wr + i * 16 + (lane & 15);
        ar[i] = rr * 4 + ((lane >> 4) ^ ((rr >> 1) & 3));
        int nn = wc + i * 16 + (lane & 15);
        br[i] = nn * 4 + ((lane >> 4) ^ ((nn >> 1) & 3));
    }

    f32x4 acc[4][4];
#pragma unroll
    for (int i = 0; i < 4; ++i)
#pragma unroll
        for (int j = 0; j < 4; ++j)
            acc[i][j] = (f32x4){0.f, 0.f, 0.f, 0.f};

    auto stage = [&](int buf, int kk) {
        gload_lds16(ag0 + kk, &As[buf][sp0 & ~63]);
        gload_lds16(ag1 + kk, &As[buf][sp1 & ~63]);
        gload_lds16(bg0 + kk, &Bs[buf][sp0 & ~63]);
        gload_lds16(bg1 + kk, &Bs[buf][sp1 & ~63]);
    };

    const int nt = K >> 5;
    stage(0, 0);
    __syncthreads();
    int cur = 0;
    for (int t = 0; t < nt; ++t) {
        if (t + 1 < nt) stage(cur ^ 1, (t + 1) * 32);
        short8v af[4], bf[4];
#pragma unroll
        for (int i = 0; i < 4; ++i) af[i] = As[cur][ar[i]];
#pragma unroll
        for (int j = 0; j < 4; ++j) bf[j] = Bs[cur][br[j]];
#pragma unroll
        for (int i = 0; i < 4; ++i)
#pragma unroll
            for (int j = 0; j < 4; ++j)
                acc[i][j] = __builtin_amdgcn_mfma_f32_16x16x32_bf16(af[i], bf[j], acc[i][j], 0, 0, 0);
        __syncthreads();
        cur ^= 1;
    }

    float bj[4];
#pragma unroll
    for (int j = 0; j < 4; ++j)
        bj[j] = bias[col0 + wc + j * 16 + (lane & 15)];
#pragma unroll
    for (int i = 0; i < 4; ++i) {
#pragma unroll
        for (int rr = 0; rr < 4; ++rr) {
            int row = row0 + wr + i * 16 + (lane >> 4) * 4 + rr;
            if (row < M) {
                size_t base = (size_t)row * HH + col0 + wc + (lane & 15);
                if (outF) {
                    float* op = outF + base;
#pragma unroll
                    for (int j = 0; j < 4; ++j) op[j * 16] = acc[i][j][rr] + bj[j];
                }
                if (outB) {
                    short* op = outB + base;
#pragma unroll
                    for (int j = 0; j < 4; ++j) op[j * 16] = f2bf(acc[i][j][rr] + bj[j]);
                }
            }
        }
    }
}

// ---------------- fused DNN layer: full-row GEMM + tanh + LN [+res LN][+cls]
// BM=32 rows/block, BN=512 (full width), BK=32, 4 waves (each 32x128).
// x2 = LN1(tanh(X@WT^T + bias)); if sc: x = LN2(tanh(sc + x2)) else x = x2
// writes outB (bf16), outF (fp32), and/or cls = sigmoid(x . cW + cb).
__global__ __launch_bounds__(256)
void mfma_dnn(const short* __restrict__ X, const short* __restrict__ WT,
              const float* __restrict__ bias,
              const float* __restrict__ g1, const float* __restrict__ b1,
              const float* __restrict__ scp,
              const float* __restrict__ g2, const float* __restrict__ b2,
              short* __restrict__ outB, float* __restrict__ outF,
              const float* __restrict__ cWp, const float* __restrict__ cbp,
              float* __restrict__ outCls, int M)
{
    __shared__ short8v As[128];     // 32 rows x 4 chunks
    __shared__ short8v Bs[2048];    // 512 cols x 4 chunks (32 KB)
    __shared__ float red[4][32][2];
    __shared__ float lnp[32][2];

    const int tid = threadIdx.x;
    const int lane = tid & 63;
    const int w = tid >> 6;

    const int nwg = M >> 5;                    // 625
    const int q = nwg >> 3, r = nwg & 7;
    int id = blockIdx.x;
    int xcd = id & 7, wi = id >> 3;
    int wgid = (xcd < r ? xcd * (q + 1) : r * (q + 1) + (xcd - r) * q) + wi;
    const int row0 = wgid * 32;

    // staging source pointers
    const int bslotbase = w * 512;
    const short* bgp[8];
#pragma unroll
    for (int g = 0; g < 8; ++g) {
        int p = bslotbase + g * 64 + lane;
        int col = p >> 2;
        int ch = (p & 3) ^ ((col >> 1) & 3);
        bgp[g] = WT + (size_t)col * HH + ch * 8;
    }
    const short* agp[2];
    if (w == 0) {
#pragma unroll
        for (int g = 0; g < 2; ++g) {
            int p = g * 64 + lane;
            int row = p >> 2;
            int ch = (p & 3) ^ ((row >> 1) & 3);
            agp[g] = X + (size_t)(row0 + row) * HH + ch * 8;
        }
    }

    int afr[2], bfr[8];
#pragma unroll
    for (int i = 0; i < 2; ++i) {
        int rw = i * 16 + (lane & 15);
        afr[i] = rw * 4 + ((lane >> 4) ^ ((rw >> 1) & 3));
    }
#pragma unroll
    for (int j = 0; j < 8; ++j) {
        int cc = w * 128 + j * 16 + (lane & 15);
        bfr[j] = cc * 4 + ((lane >> 4) ^ ((cc >> 1) & 3));
    }

    f32x4 acc[2][8];
#pragma unroll
    for (int i = 0; i < 2; ++i)
#pragma unroll
        for (int j = 0; j < 8; ++j)
            acc[i][j] = (f32x4){0.f, 0.f, 0.f, 0.f};

    for (int t = 0; t < 16; ++t) {
        int kk = t * 32;
#pragma unroll
        for (int g = 0; g < 8; ++g)
            gload_lds16(bgp[g] + kk, &Bs[bslotbase + g * 64]);
        if (w == 0) {
#pragma unroll
            for (int g = 0; g < 2; ++g)
                gload_lds16(agp[g] + kk, &As[g * 64]);
        }
        __syncthreads();
        short8v af[2], bf[8];
#pragma unroll
        for (int i = 0; i < 2; ++i) af[i] = As[afr[i]];
#pragma unroll
        for (int j = 0; j < 8; ++j) bf[j] = Bs[bfr[j]];
#pragma unroll
        for (int i = 0; i < 2; ++i)
#pragma unroll
            for (int j = 0; j < 8; ++j)
                acc[i][j] = __builtin_amdgcn_mfma_f32_16x16x32_bf16(af[i], bf[j], acc[i][j], 0, 0, 0);
        __syncthreads();
    }

    // ---------------- epilogue ----------------
    const int colb = w * 128 + (lane & 15);
    float bj[8], g1j[8], b1j[8];
#pragma unroll
    for (int j = 0; j < 8; ++j) {
        bj[j]  = bias[colb + j * 16];
        g1j[j] = g1[colb + j * 16];
        b1j[j] = b1[colb + j * 16];
    }
    // t = tanh(z)
#pragma unroll
    for (int i = 0; i < 2; ++i)
#pragma unroll
        for (int j = 0; j < 8; ++j)
#pragma unroll
            for (int rr = 0; rr < 4; ++rr)
                acc[i][j][rr] = tanhf(acc[i][j][rr] + bj[j]);

    // LN1 reduction
    {
        float s1[2][4], s2[2][4];
#pragma unroll
        for (int i = 0; i < 2; ++i)
#pragma unroll
            for (int rr = 0; rr < 4; ++rr) {
                float s = 0.f, ss = 0.f;
#pragma unroll
                for (int j = 0; j < 8; ++j) {
                    float v = acc[i][j][rr];
                    s += v; ss = fmaf(v, v, ss);
                }
#pragma unroll
                for (int m = 1; m <= 8; m <<= 1) {
                    s += __shfl_xor(s, m); ss += __shfl_xor(ss, m);
                }
                s1[i][rr] = s; s2[i][rr] = ss;
            }
        if ((lane & 15) == 0) {
#pragma unroll
            for (int i = 0; i < 2; ++i)
#pragma unroll
                for (int rr = 0; rr < 4; ++rr) {
                    int row = i * 16 + (lane >> 4) * 4 + rr;
                    red[w][row][0] = s1[i][rr];
                    red[w][row][1] = s2[i][rr];
                }
        }
        __syncthreads();
        if (tid < 32) {
            float s = red[0][tid][0] + red[1][tid][0] + red[2][tid][0] + red[3][tid][0];
            float ss = red[0][tid][1] + red[1][tid][1] + red[2][tid][1] + red[3][tid][1];
            float mu = s * (1.f / HH);
            float var = ss * (1.f / HH) - mu * mu;
            lnp[tid][0] = mu; lnp[tid][1] = rsqrtf(var + 1e-5f);
        }
        __syncthreads();
    }
    // x2 = (t-mu)*rs*g1 + b1
#pragma unroll
    for (int i = 0; i < 2; ++i)
#pragma unroll
        for (int rr = 0; rr < 4; ++rr) {
            int row = i * 16 + (lane >> 4) * 4 + rr;
            float mu = lnp[row][0], rs = lnp[row][1];
#pragma unroll
            for (int j = 0; j < 8; ++j)
                acc[i][j][rr] = (acc[i][j][rr] - mu) * rs * g1j[j] + b1j[j];
        }

    if (scp) {
        // y = tanh(sc + x2)
#pragma unroll
        for (int i = 0; i < 2; ++i)
#pragma unroll
            for (int rr = 0; rr < 4; ++rr) {
                int row = i * 16 + (lane >> 4) * 4 + rr;
                const float* sp = scp + (size_t)(row0 + row) * HH;
#pragma unroll
                for (int j = 0; j < 8; ++j)
                    acc[i][j][rr] = tanhf(sp[colb + j * 16] + acc[i][j][rr]);
            }
        __syncthreads();   // ensure lnp round-1 reads done before red reuse
        float s1[2][4], s2[2][4];
#pragma unroll
        for (int i = 0; i < 2; ++i)
#pragma unroll
            for (int rr = 0; rr < 4; ++rr) {
                float s = 0.f, ss = 0.f;
#pragma unroll
                for (int j = 0; j < 8; ++j) {
                    float v = acc[i][j][rr];
                    s += v; ss = fmaf(v, v, ss);
                }
#pragma unroll
                for (int m = 1; m <= 8; m <<= 1) {
                    s += __shfl_xor(s, m); ss += __shfl_xor(ss, m);
                }
                s1[i][rr] = s; s2[i][rr] = ss;
            }
        if ((lane & 15) == 0) {
#pragma unroll
            for (int i = 0; i < 2; ++i)
#pragma unroll
                for (int rr = 0; rr < 4; ++rr) {
                    int row = i * 16 + (lane >> 4) * 4 + rr;
                    red[w][row][0] = s1[i][rr];
                    red[w][row][1] = s2[i][rr];
                }
        }
        __syncthreads();
        if (tid < 32) {
            float s = red[0][tid][0] + red[1][tid][0] + red[2][tid][0] + red[3][tid][0];
            float ss = red[0][tid][1] + red[1][tid][1] + red[2][tid][1] + red[3][tid][1];
            float mu = s * (1.f / HH);
            float var = ss * (1.f / HH) - mu * mu;
            lnp[tid][0] = mu; lnp[tid][1] = rsqrtf(var + 1e-5f);
        }
        __syncthreads();
        float g2j[8], b2j[8];
#pragma unroll
        for (int j = 0; j < 8; ++j) {
            g2j[j] = g2[colb + j * 16];
            b2j[j] = b2[colb + j * 16];
        }
#pragma unroll
        for (int i = 0; i < 2; ++i)
#pragma unroll
            for (int rr = 0; rr < 4; ++rr) {
                int row = i * 16 + (lane >> 4) * 4 + rr;
                float mu = lnp[row][0], rs = lnp[row][1];
#pragma unroll
                for (int j = 0; j < 8; ++j)
                    acc[i][j][rr] = (acc[i][j][rr] - mu) * rs * g2j[j] + b2j[j];
            }
    }

    // stores
    if (outB) {
#pragma unroll
        for (int i = 0; i < 2; ++i)
#pragma unroll
            for (int rr = 0; rr < 4; ++rr) {
                int row = row0 + i * 16 + (lane >> 4) * 4 + rr;
                short* op = outB + (size_t)row * HH + colb;
#pragma unroll
                for (int j = 0; j < 8; ++j) op[j * 16] = f2bf(acc[i][j][rr]);
            }
    }
    if (outF) {
#pragma unroll
        for (int i = 0; i < 2; ++i)
#pragma unroll
            for (int rr = 0; rr < 4; ++rr) {
                int row = row0 + i * 16 + (lane >> 4) * 4 + rr;
                float* op = outF + (size_t)row * HH + colb;
#pragma unroll
                for (int j = 0; j < 8; ++j) op[j * 16] = acc[i][j][rr];
            }
    }
    if (cWp) {
        float cw[8];
#pragma unroll
        for (int j = 0; j < 8; ++j) cw[j] = cWp[colb + j * 16];
        __syncthreads();   // red reuse
        float d[2][4];
#pragma unroll
        for (int i = 0; i < 2; ++i)
#pragma unroll
            for (int rr = 0; rr < 4; ++rr) {
                float s = 0.f;
#pragma unroll
                for (int j = 0; j < 8; ++j) s = fmaf(acc[i][j][rr], cw[j], s);
#pragma unroll
                for (int m = 1; m <= 8; m <<= 1) s += __shfl_xor(s, m);
                d[i][rr] = s;
            }
        if ((lane & 15) == 0) {
#pragma unroll
            for (int i = 0; i < 2; ++i)
#pragma unroll
                for (int rr = 0; rr < 4; ++rr)
                    red[w][i * 16 + (lane >> 4) * 4 + rr][0] = d[i][rr];
        }
        __syncthreads();
        if (tid < 32) {
            float s = red[0][tid][0] + red[1][tid][0] + red[2][tid][0] + red[3][tid][0];
            outCls[row0 + tid] = 1.f / (1.f + expf(-(s + cbp[0])));
        }
    }
}

// ---------------- gat_pre: u = fW @ aw[:512], v = fW @ aw[512:], fb dots -----
__global__ __launch_bounds__(256)
void gat_pre_kernel(const float* __restrict__ fW, const float* __restrict__ fb,
                    const float* __restrict__ aw, float* __restrict__ uv,
                    float* __restrict__ s0t0)
{
    int row = blockIdx.x * 4 + (threadIdx.x >> 6);
    int lane = threadIdx.x & 63;
    const float4* ah = (const float4*)aw;
    const float4* at = (const float4*)(aw + HH);
    const float4* fp;
    if (row < 512)      fp = (const float4*)(fW + (size_t)row * HH);
    else if (row == 512) fp = (const float4*)fb;
    else return;
    float du = 0.f, dv = 0.f;
#pragma unroll
    for (int l = 0; l < 2; ++l) {
        int idx = lane * 2 + l;
        float4 f = fp[idx], a = ah[idx], b = at[idx];
        du += f.x*a.x + f.y*a.y + f.z*a.z + f.w*a.w;
        dv += f.x*b.x + f.y*b.y + f.z*b.z + f.w*b.w;
    }
#pragma unroll
    for (int m = 32; m >= 1; m >>= 1) {
        du += __shfl_xor(du, m);
        dv += __shfl_xor(dv, m);
    }
    if (lane == 0) {
        if (row < 512) { uv[row] = du; uv[512 + row] = dv; }
        else           { s0t0[0] = du; s0t0[1] = dv; }
    }
}

// ---------------- rowdot2: ss[n]=Head[n].u+s0, ts[n]=Tail[n].v+t0 (bf16 rows)
__global__ __launch_bounds__(256)
void rowdot2_kernel(const short* __restrict__ Hd, const short* __restrict__ Tl,
                    const float* __restrict__ uv, const float* __restrict__ s0t0,
                    float* __restrict__ ss, float* __restrict__ ts, int N)
{
    int row = blockIdx.x * 4 + (threadIdx.x >> 6);
    int lane = threadIdx.x & 63;
    if (row >= N) return;
    short8v h = ((const short8v*)(Hd + (size_t)row * HH))[lane];
    short8v t = ((const short8v*)(Tl + (size_t)row * HH))[lane];
    const float4* up = (const float4*)uv + lane * 2;
    const float4* vp = (const float4*)(uv + HH) + lane * 2;
    float4 u0 = up[0], u1 = up[1], v0 = vp[0], v1 = vp[1];
    float a = bf2f(h[0])*u0.x + bf2f(h[1])*u0.y + bf2f(h[2])*u0.z + bf2f(h[3])*u0.w
            + bf2f(h[4])*u1.x + bf2f(h[5])*u1.y + bf2f(h[6])*u1.z + bf2f(h[7])*u1.w;
    float b = bf2f(t[0])*v0.x + bf2f(t[1])*v0.y + bf2f(t[2])*v0.z + bf2f(t[3])*v0.w
            + bf2f(t[4])*v1.x + bf2f(t[5])*v1.y + bf2f(t[6])*v1.z + bf2f(t[7])*v1.w;
#pragma unroll
    for (int m = 32; m >= 1; m >>= 1) {
        a += __shfl_xor(a, m);
        b += __shfl_xor(b, m);
    }
    if (lane == 0) { ss[row] = a + s0t0[0]; ts[row] = b + s0t0[1]; }
}

// ---------------- CSR build (both relations, hoisted) ----------------
__global__ __launch_bounds__(256)
void count2_kernel(const int* __restrict__ s0, const int* __restrict__ s1,
                   int* __restrict__ c0, int* __restrict__ c1, int E)
{
    int i = blockIdx.x * blockDim.x + threadIdx.x;
    if (i < E) atomicAdd(&c0[s0[i]], 1);
    else if (i < 2 * E) atomicAdd(&c1[s1[i - E]], 1);
}

__global__ __launch_bounds__(1024)
void scan2_kernel(const int* __restrict__ c0, const int* __restrict__ c1,
                  int* __restrict__ o0, int* __restrict__ o1,
                  int* __restrict__ u0, int* __restrict__ u1, int n)
{
    const int* counts = blockIdx.x ? c1 : c0;
    int* offs = blockIdx.x ? o1 : o0;
    int* curs = blockIdx.x ? u1 : u0;
    __shared__ int part[1024];
    const int tid = threadIdx.x;
    const int CH = (n + 1023) / 1024;
    const int base = tid * CH;
    int s = 0;
    for (int i = 0; i < CH; ++i) {
        int idx = base + i;
        if (idx < n) s += counts[idx];
    }
    part[tid] = s;
    __syncthreads();
    for (int d = 1; d < 1024; d <<= 1) {
        int v = 0;
        if (tid >= d) v = part[tid - d];
        __syncthreads();
        if (tid >= d) part[tid] += v;
        __syncthreads();
    }
    int run = (tid == 0) ? 0 : part[tid - 1];
    for (int i = 0; i < CH; ++i) {
        int idx = base + i;
        if (idx < n) { offs[idx] = run; curs[idx] = run; run += counts[idx]; }
    }
    if (tid == 1023) offs[n] = run;
}

// fill CSR with target ids AND precomputed edge weights
__global__ __launch_bounds__(256)
void fill_kernel(const int* __restrict__ src, const int* __restrict__ tgt,
                 const float* __restrict__ ss, const float* __restrict__ ts,
                 const float* __restrict__ ab_ptr, int* __restrict__ cursor,
                 int* __restrict__ tvals, float* __restrict__ wv, int E)
{
    int i = blockIdx.x * blockDim.x + threadIdx.x;
    if (i >= E) return;
    int s = src[i], t = tgt[i];
    int pos = atomicAdd(&cursor[s], 1);
    tvals[pos] = t;
    wv[pos] = expf(tanhf(ss[s] + ts[t] + ab_ptr[0]));
}

// ---------------- fused GAT aggregate + combine (bf16 rows) -----------------
// out[s,:] = (head[s,:] + (sum_j w_j T[t_j,:]) / (sum_j w_j) + gbias) * 0.5
// 4-wide unrolled gather: 4 independent row loads in flight.
__global__ __launch_bounds__(256)
void gat_agg_kernel(const int* __restrict__ offs, const int* __restrict__ tvals,
                    const float* __restrict__ wv, const short* __restrict__ T,
                    const short* __restrict__ head, const float* __restrict__ gbias,
                    short* __restrict__ out, int N)
{
    int s = blockIdx.x * 4 + (threadIdx.x >> 6);
    int lane = threadIdx.x & 63;
    if (s >= N) return;
    const int beg = offs[s], end = offs[s + 1];
    float a[8];
#pragma unroll
    for (int q = 0; q < 8; ++q) a[q] = 0.f;
    float den = 0.f;

    int j = beg;
    for (; j + 4 <= end; j += 4) {
        int t0 = tvals[j], t1 = tvals[j + 1], t2 = tvals[j + 2], t3 = tvals[j + 3];
        float w0 = wv[j], w1 = wv[j + 1], w2 = wv[j + 2], w3 = wv[j + 3];
        short8v v0 = ((const short8v*)(T + (size_t)t0 * HH))[lane];
        short8v v1 = ((const short8v*)(T + (size_t)t1 * HH))[lane];
        short8v v2 = ((const short8v*)(T + (size_t)t2 * HH))[lane];
        short8v v3 = ((const short8v*)(T + (size_t)t3 * HH))[lane];
        den += w0 + w1 + w2 + w3;
#pragma unroll
        for (int q = 0; q < 8; ++q) {
            float acc = a[q];
            acc = fmaf(w0, bf2f(v0[q]), acc);
            acc = fmaf(w1, bf2f(v1[q]), acc);
            acc = fmaf(w2, bf2f(v2[q]), acc);
            acc = fmaf(w3, bf2f(v3[q]), acc);
            a[q] = acc;
        }
    }
    for (; j < end; ++j) {
        int t = tvals[j];
        float w = wv[j];
        short8v tv = ((const short8v*)(T + (size_t)t * HH))[lane];
        den += w;
#pragma unroll
        for (int q = 0; q < 8; ++q) a[q] = fmaf(w, bf2f(tv[q]), a[q]);
    }
    float inv = (den > 0.f) ? 1.f / den : 0.f;

    short8v h = ((const short8v*)(head + (size_t)s * HH))[lane];
    const float4* bp = (const float4*)gbias + lane * 2;
    float4 b0 = bp[0], b1 = bp[1];
    float bb[8] = {b0.x, b0.y, b0.z, b0.w, b1.x, b1.y, b1.z, b1.w};
    short8v o;
#pragma unroll
    for (int q = 0; q < 8; ++q)
        o[q] = f2bf((bf2f(h[q]) + a[q] * inv + bb[q]) * 0.5f);
    ((short8v*)(out + (size_t)s * HH))[lane] = o;
}

extern "C" void kernel_launch(void* const* d_in, const int* in_sizes, int n_in,
                              void* d_out, int out_size, void* d_ws, size_t ws_size,
                              hipStream_t stream)
{
    (void)in_sizes; (void)n_in; (void)out_size; (void)ws_size;
    const int N = NN, E = NE, H = HH;
    const size_t NHf = (size_t)N * H;

    const float* fu0 = (const float*)d_in[0];
    const float* fi1 = (const float*)d_in[3];
    const float* fu2 = (const float*)d_in[4];
    const int* eUI0 = (const int*)d_in[6];
    const int* eIU1 = (const int*)d_in[9];
    const float* Wu  = (const float*)d_in[10];
    const float* bu  = (const float*)d_in[11];
    const float* Wi  = (const float*)d_in[12];
    const float* bi  = (const float*)d_in[13];
    const float* gfW = (const float*)d_in[14];
    const float* gfb = (const float*)d_in[15];
    const float* gaw = (const float*)d_in[16];
    const float* gab = (const float*)d_in[17];
    const float* gbias = (const float*)d_in[18];
    const float* prW = (const float*)d_in[19];
    const float* prb = (const float*)d_in[20];
    const float* dW  = (const float*)d_in[21];
    const float* db  = (const float*)d_in[22];
    const float* dlg = (const float*)d_in[23];
    const float* dlb = (const float*)d_in[24];
    const float* rlg = (const float*)d_in[25];
    const float* rlb = (const float*)d_in[26];
    const float* cW  = (const float*)d_in[27];
    const float* cb  = (const float*)d_in[28];

    // fp32 region
    float* B5   = (float*)d_ws;      // residual sc (fp32)
    float* ssb  = B5 + NHf;          // [N]
    float* tsb  = ssb + N;           // [N]
    float* uv   = tsb + N;           // [1024]
    float* s0t0 = uv + 1024;         // [2] (+pad)
    float* wvb  = s0t0 + 4;          // [E]
    int* counts0 = (int*)(wvb + E);  // [N]
    int* counts1 = counts0 + N;      // [N]
    int* offs0   = counts1 + N;      // [N+1]
    int* offs1   = offs0 + N + 1;    // [N+1]
    int* cur0    = offs1 + N + 1;    // [N]
    int* cur1    = cur0 + N;         // [N]
    int* tvals   = cur1 + N;         // [E]
    size_t boff = (size_t)((char*)(tvals + E) - (char*)d_ws);
    boff = (boff + 15) & ~(size_t)15;
    // bf16 activations
    short* S0    = (short*)((char*)d_ws + boff); // [2*NHf]: fu2 bf16, fu0 bf16
    short* SUHU  = S0 + 2 * NHf;                 // [2*NHf]: su, hu0
    short* XI1   = SUHU + 2 * NHf;               // [NHf/2] raw item feat
    short* HI    = XI1 + NHf / 2;                // hi
    short* SINEW = HI + NHf;                     // si_new ; later XB
    short* T4    = SINEW + NHf;                  // gat tail transform
    short* SUF   = T4 + NHf;                     // su_final
    short* WTu   = SUF + NHf;
    short* WTi   = WTu + 512 * 512;
    short* WTg0  = WTi + 512 * 256;
    short* WTg1  = WTg0 + 512 * 512;
    short* WTpr  = WTg1 + 512 * 512;
    short* WTd   = WTpr + 512 * 512;             // 4 x 512*512
    short* SU  = SUHU;
    short* HU0 = SUHU + NHf;
    short* XB  = SINEW;   // alias after GAT0 done

    // ---- weight pre-pass ----
    auto WTR = [&](const float* src, short* dst, int K) {
        hipLaunchKernelGGL(wtr_kernel, dim3(16, K / 32), dim3(32, 8), 0, stream,
                           src, dst, K, 512);
    };
    WTR(Wu, WTu, 512);
    WTR(Wi, WTi, 256);
    WTR(gfW, WTg0, 512);
    WTR(gfW + (size_t)H * H, WTg1, 512);
    WTR(prW, WTpr, 512);
    for (int k = 0; k < 4; ++k)
        WTR(dW + (size_t)k * H * H, WTd + (size_t)k * 512 * 512, 512);

    auto F2B = [&](const float* src, short* dst, size_t n) {
        int n8 = (int)(n / 8);
        hipLaunchKernelGGL(f2b_kernel, dim3((n8 + 255) / 256), dim3(256), 0, stream,
                           src, dst, n8);
    };

    // ---- CSR build ----
    hipMemsetAsync(counts0, 0, 2 * N * sizeof(int), stream);
    hipLaunchKernelGGL(count2_kernel, dim3((2 * E + 255) / 256), dim3(256), 0, stream,
                       eUI0, eIU1, counts0, counts1, E);
    hipLaunchKernelGGL(scan2_kernel, dim3(2), dim3(1024), 0, stream,
                       counts0, counts1, offs0, offs1, cur0, cur1, N);

    auto MLIN = [&](const short* X, const short* WT, const float* b,
                    float* oF, short* oB, int M, int K) {
        int nwg = ((M + 127) / 128) * 4;
        hipLaunchKernelGGL(mfma_lin, dim3(nwg), dim3(256), 0, stream,
                           X, WT, b, oF, oB, M, K);
    };
    const int rgrid = (N + 3) / 4;
    const int egrid = (E + 255) / 256;

    auto GAT = [&](int r, const short* headB, const short* tailB, const short* WTg,
                   const int* edges, int* offs, int* curs, short* outB) {
        hipLaunchKernelGGL(gat_pre_kernel, dim3(130), dim3(256), 0, stream,
                           gfW + (size_t)r * H * H, gfb + r * H, gaw + (size_t)r * 2 * H,
                           uv, s0t0);
        MLIN(tailB, WTg, gfb + r * H, nullptr, T4, N, 512);
        hipLaunchKernelGGL(rowdot2_kernel, dim3(rgrid), dim3(256), 0, stream,
                           headB, tailB, uv, s0t0, ssb, tsb, N);
        hipLaunchKernelGGL(fill_kernel, dim3(egrid), dim3(256), 0, stream,
                           edges, edges + E, ssb, tsb, gab + r, curs, tvals, wvb, E);
        hipLaunchKernelGGL(gat_agg_kernel, dim3(rgrid), dim3(256), 0, stream,
                           offs, tvals, wvb, T4, headB, gbias + (size_t)r * H, outB, N);
    };

    // input transforms (su & hu0 batched: M = 2N over contiguous S0 -> SUHU)
    F2B(fu2, S0, NHf);
    F2B(fu0, S0 + NHf, NHf);
    F2B(fi1, XI1, NHf / 2);
    MLIN(S0, WTu, bu, nullptr, SUHU, 2 * N, 512);     // su + hu0
    MLIN(XI1, WTi, bi, nullptr, HI, N, 256);          // hi
    GAT(1, HI, SU, WTg1, eIU1, offs1, cur1, SINEW);   // si_new
    GAT(0, HU0, SINEW, WTg0, eUI0, offs0, cur0, SUF); // su_final

    // Res_DNN head: prep (dual-write sc fp32 + x bf16), then 4 fused layers
    MLIN(SUF, WTpr, prb, B5, XB, N, 512);
    const int dgrid = N / 32;   // 625
    // r=0, d=0
    hipLaunchKernelGGL(mfma_dnn, dim3(dgrid), dim3(256), 0, stream,
                       XB, WTd, db, dlg, dlb,
                       (const float*)nullptr, (const float*)nullptr, (const float*)nullptr,
                       XB, (float*)nullptr,
                       (const float*)nullptr, (const float*)nullptr, (float*)nullptr, N);
    // r=0, d=1 + res-LN (writes new sc fp32 + x bf16)
    hipLaunchKernelGGL(mfma_dnn, dim3(dgrid), dim3(256), 0, stream,
                       XB, WTd + (size_t)1 * 512 * 512, db + H, dlg + H, dlb + H,
                       B5, rlg, rlb,
                       XB, B5,
                       (const float*)nullptr, (const float*)nullptr, (float*)nullptr, N);
    // r=1, d=0
    hipLaunchKernelGGL(mfma_dnn, dim3(dgrid), dim3(256), 0, stream,
                       XB, WTd + (size_t)2 * 512 * 512, db + 2 * H, dlg + 2 * H, dlb + 2 * H,
                       (const float*)nullptr, (const float*)nullptr, (const float*)nullptr,
                       XB, (float*)nullptr,
                       (const float*)nullptr, (const float*)nullptr, (float*)nullptr, N);
    // r=1, d=1 + res-LN + classifier -> d_out
    hipLaunchKernelGGL(mfma_dnn, dim3(dgrid), dim3(256), 0, stream,
                       XB, WTd + (size_t)3 * 512 * 512, db + 3 * H, dlg + 3 * H, dlb + 3 * H,
                       B5, rlg + H, rlb + H,
                       (short*)nullptr, (float*)nullptr,
                       cW, cb, (float*)d_out, N);
}

// Round 7
// 586.621 us; speedup vs baseline: 1.2270x; 1.2270x over previous
//
#include <hip/hip_runtime.h>
#include <math.h>

#define NN 20000
#define NE 200000
#define HH 512

typedef __attribute__((ext_vector_type(8))) short short8v;
typedef __attribute__((ext_vector_type(4))) float f32x4;

__device__ inline short f2bf(float f) {
    union { float f; unsigned u; } v; v.f = f;
    unsigned r = (v.u + 0x7fffu + ((v.u >> 16) & 1u)) >> 16;
    return (short)r;
}
__device__ inline float bf2f(short s) {
    union { unsigned u; float f; } v;
    v.u = ((unsigned)(unsigned short)s) << 16;
    return v.f;
}

// direct global->LDS DMA, 16B per lane; lds dest must be wave-uniform base
__device__ inline void gload_lds16(const void* g, void* l) {
    __builtin_amdgcn_global_load_lds(
        (const __attribute__((address_space(1))) void*)g,
        (__attribute__((address_space(3))) void*)l, 16, 0, 0);
}

// ---------------- fp32 -> bf16 bulk convert (8 elems/thread) ----------------
__global__ __launch_bounds__(256)
void f2b_kernel(const float* __restrict__ src, short* __restrict__ dst, int n8)
{
    int i = blockIdx.x * 256 + threadIdx.x;
    if (i >= n8) return;
    const float4* p = (const float4*)src + (size_t)i * 2;
    float4 a = p[0], b = p[1];
    short8v s;
    s[0] = f2bf(a.x); s[1] = f2bf(a.y); s[2] = f2bf(a.z); s[3] = f2bf(a.w);
    s[4] = f2bf(b.x); s[5] = f2bf(b.y); s[6] = f2bf(b.z); s[7] = f2bf(b.w);
    ((short8v*)dst)[i] = s;
}

// ---------------- weight transpose + bf16 convert: dst[n][k] = src[k][n] ----
__global__ __launch_bounds__(256)
void wtr_kernel(const float* __restrict__ src, short* __restrict__ dst,
                int K, int Ncols)
{
    __shared__ float t[32][33];
    int bx = blockIdx.x * 32;
    int by = blockIdx.y * 32;
    int tx = threadIdx.x, ty = threadIdx.y;
    for (int i = ty; i < 32; i += 8)
        t[i][tx] = src[(size_t)(by + i) * Ncols + bx + tx];
    __syncthreads();
    for (int i = ty; i < 32; i += 8)
        dst[(size_t)(bx + i) * K + by + tx] = f2bf(t[tx][i]);
}

// ---------------- MFMA GEMM: out[M,512] = X[M,K](bf16) @ WT[512,K](bf16)^T + b
// 128x128 tile, BK=32, 4 waves (2x2), wave 64x64 (4x4 frags of 16x16x32).
__global__ __launch_bounds__(256)
void mfma_lin(const short* __restrict__ X, const short* __restrict__ WT,
              const float* __restrict__ bias, float* __restrict__ outF,
              short* __restrict__ outB, int M, int K)
{
    __shared__ short8v As[2][512];   // [row 0..127][chunk-slot 0..3]
    __shared__ short8v Bs[2][512];

    const int tid = threadIdx.x;
    const int lane = tid & 63;
    const int w = tid >> 6;

    const int nby = (M + 127) >> 7;
    const int nwg = nby << 2;
    const int q = nwg >> 3, r = nwg & 7;
    int id = blockIdx.x;
    int xcd = id & 7, wi = id >> 3;
    int wgid = (xcd < r ? xcd * (q + 1) : r * (q + 1) + (xcd - r) * q) + wi;
    const int col0 = (wgid & 3) * 128;
    const int row0 = (wgid >> 2) * 128;

    const int wr = (w >> 1) * 64;
    const int wc = (w & 1) * 64;

    int sp0 = w * 128 + lane;
    int sp1 = sp0 + 64;
    int r0_ = sp0 >> 2, r1_ = sp1 >> 2;
    int c0_ = (sp0 & 3) ^ ((r0_ >> 1) & 3);
    int c1_ = (sp1 & 3) ^ ((r1_ >> 1) & 3);
    int ga0 = row0 + r0_; if (ga0 >= M) ga0 = M - 1;
    int ga1 = row0 + r1_; if (ga1 >= M) ga1 = M - 1;
    const short* ag0 = X + (size_t)ga0 * K + c0_ * 8;
    const short* ag1 = X + (size_t)ga1 * K + c1_ * 8;
    const short* bg0 = WT + (size_t)(col0 + r0_) * K + c0_ * 8;
    const short* bg1 = WT + (size_t)(col0 + r1_) * K + c1_ * 8;

    int ar[4], br[4];
#pragma unroll
    for (int i = 0; i < 4; ++i) {
        int rr = wr + i * 16 + (lane & 15);
        ar[i] = rr * 4 + ((lane >> 4) ^ ((rr >> 1) & 3));
        int nn = wc + i * 16 + (lane & 15);
        br[i] = nn * 4 + ((lane >> 4) ^ ((nn >> 1) & 3));
    }

    f32x4 acc[4][4];
#pragma unroll
    for (int i = 0; i < 4; ++i)
#pragma unroll
        for (int j = 0; j < 4; ++j)
            acc[i][j] = (f32x4){0.f, 0.f, 0.f, 0.f};

    auto stage = [&](int buf, int kk) {
        gload_lds16(ag0 + kk, &As[buf][sp0 & ~63]);
        gload_lds16(ag1 + kk, &As[buf][sp1 & ~63]);
        gload_lds16(bg0 + kk, &Bs[buf][sp0 & ~63]);
        gload_lds16(bg1 + kk, &Bs[buf][sp1 & ~63]);
    };

    const int nt = K >> 5;
    stage(0, 0);
    __syncthreads();
    int cur = 0;
    for (int t = 0; t < nt; ++t) {
        if (t + 1 < nt) stage(cur ^ 1, (t + 1) * 32);
        short8v af[4], bf[4];
#pragma unroll
        for (int i = 0; i < 4; ++i) af[i] = As[cur][ar[i]];
#pragma unroll
        for (int j = 0; j < 4; ++j) bf[j] = Bs[cur][br[j]];
#pragma unroll
        for (int i = 0; i < 4; ++i)
#pragma unroll
            for (int j = 0; j < 4; ++j)
                acc[i][j] = __builtin_amdgcn_mfma_f32_16x16x32_bf16(af[i], bf[j], acc[i][j], 0, 0, 0);
        __syncthreads();
        cur ^= 1;
    }

    float bj[4];
#pragma unroll
    for (int j = 0; j < 4; ++j)
        bj[j] = bias[col0 + wc + j * 16 + (lane & 15)];
#pragma unroll
    for (int i = 0; i < 4; ++i) {
#pragma unroll
        for (int rr = 0; rr < 4; ++rr) {
            int row = row0 + wr + i * 16 + (lane >> 4) * 4 + rr;
            if (row < M) {
                size_t base = (size_t)row * HH + col0 + wc + (lane & 15);
                if (outF) {
                    float* op = outF + base;
#pragma unroll
                    for (int j = 0; j < 4; ++j) op[j * 16] = acc[i][j][rr] + bj[j];
                }
                if (outB) {
                    short* op = outB + base;
#pragma unroll
                    for (int j = 0; j < 4; ++j) op[j * 16] = f2bf(acc[i][j][rr] + bj[j]);
                }
            }
        }
    }
}

// ---------------- gat_pre: u = fW @ aw[:512], v = fW @ aw[512:], fb dots -----
__global__ __launch_bounds__(256)
void gat_pre_kernel(const float* __restrict__ fW, const float* __restrict__ fb,
                    const float* __restrict__ aw, float* __restrict__ uv,
                    float* __restrict__ s0t0)
{
    int row = blockIdx.x * 4 + (threadIdx.x >> 6);
    int lane = threadIdx.x & 63;
    const float4* ah = (const float4*)aw;
    const float4* at = (const float4*)(aw + HH);
    const float4* fp;
    if (row < 512)      fp = (const float4*)(fW + (size_t)row * HH);
    else if (row == 512) fp = (const float4*)fb;
    else return;
    float du = 0.f, dv = 0.f;
#pragma unroll
    for (int l = 0; l < 2; ++l) {
        int idx = lane * 2 + l;
        float4 f = fp[idx], a = ah[idx], b = at[idx];
        du += f.x*a.x + f.y*a.y + f.z*a.z + f.w*a.w;
        dv += f.x*b.x + f.y*b.y + f.z*b.z + f.w*b.w;
    }
#pragma unroll
    for (int m = 32; m >= 1; m >>= 1) {
        du += __shfl_xor(du, m);
        dv += __shfl_xor(dv, m);
    }
    if (lane == 0) {
        if (row < 512) { uv[row] = du; uv[512 + row] = dv; }
        else           { s0t0[0] = du; s0t0[1] = dv; }
    }
}

// ---------------- rowdot2: ss[n]=Head[n].u+s0, ts[n]=Tail[n].v+t0 (bf16 rows)
__global__ __launch_bounds__(256)
void rowdot2_kernel(const short* __restrict__ Hd, const short* __restrict__ Tl,
                    const float* __restrict__ uv, const float* __restrict__ s0t0,
                    float* __restrict__ ss, float* __restrict__ ts, int N)
{
    int row = blockIdx.x * 4 + (threadIdx.x >> 6);
    int lane = threadIdx.x & 63;
    if (row >= N) return;
    short8v h = ((const short8v*)(Hd + (size_t)row * HH))[lane];
    short8v t = ((const short8v*)(Tl + (size_t)row * HH))[lane];
    const float4* up = (const float4*)uv + lane * 2;
    const float4* vp = (const float4*)(uv + HH) + lane * 2;
    float4 u0 = up[0], u1 = up[1], v0 = vp[0], v1 = vp[1];
    float a = bf2f(h[0])*u0.x + bf2f(h[1])*u0.y + bf2f(h[2])*u0.z + bf2f(h[3])*u0.w
            + bf2f(h[4])*u1.x + bf2f(h[5])*u1.y + bf2f(h[6])*u1.z + bf2f(h[7])*u1.w;
    float b = bf2f(t[0])*v0.x + bf2f(t[1])*v0.y + bf2f(t[2])*v0.z + bf2f(t[3])*v0.w
            + bf2f(t[4])*v1.x + bf2f(t[5])*v1.y + bf2f(t[6])*v1.z + bf2f(t[7])*v1.w;
#pragma unroll
    for (int m = 32; m >= 1; m >>= 1) {
        a += __shfl_xor(a, m);
        b += __shfl_xor(b, m);
    }
    if (lane == 0) { ss[row] = a + s0t0[0]; ts[row] = b + s0t0[1]; }
}

// ---------------- CSR build (both relations, hoisted) ----------------
__global__ __launch_bounds__(256)
void count2_kernel(const int* __restrict__ s0, const int* __restrict__ s1,
                   int* __restrict__ c0, int* __restrict__ c1, int E)
{
    int i = blockIdx.x * blockDim.x + threadIdx.x;
    if (i < E) atomicAdd(&c0[s0[i]], 1);
    else if (i < 2 * E) atomicAdd(&c1[s1[i - E]], 1);
}

__global__ __launch_bounds__(1024)
void scan2_kernel(const int* __restrict__ c0, const int* __restrict__ c1,
                  int* __restrict__ o0, int* __restrict__ o1,
                  int* __restrict__ u0, int* __restrict__ u1, int n)
{
    const int* counts = blockIdx.x ? c1 : c0;
    int* offs = blockIdx.x ? o1 : o0;
    int* curs = blockIdx.x ? u1 : u0;
    __shared__ int part[1024];
    const int tid = threadIdx.x;
    const int CH = (n + 1023) / 1024;
    const int base = tid * CH;
    int s = 0;
    for (int i = 0; i < CH; ++i) {
        int idx = base + i;
        if (idx < n) s += counts[idx];
    }
    part[tid] = s;
    __syncthreads();
    for (int d = 1; d < 1024; d <<= 1) {
        int v = 0;
        if (tid >= d) v = part[tid - d];
        __syncthreads();
        if (tid >= d) part[tid] += v;
        __syncthreads();
    }
    int run = (tid == 0) ? 0 : part[tid - 1];
    for (int i = 0; i < CH; ++i) {
        int idx = base + i;
        if (idx < n) { offs[idx] = run; curs[idx] = run; run += counts[idx]; }
    }
    if (tid == 1023) offs[n] = run;
}

// fill CSR with target ids AND precomputed edge weights
__global__ __launch_bounds__(256)
void fill_kernel(const int* __restrict__ src, const int* __restrict__ tgt,
                 const float* __restrict__ ss, const float* __restrict__ ts,
                 const float* __restrict__ ab_ptr, int* __restrict__ cursor,
                 int* __restrict__ tvals, float* __restrict__ wv, int E)
{
    int i = blockIdx.x * blockDim.x + threadIdx.x;
    if (i >= E) return;
    int s = src[i], t = tgt[i];
    int pos = atomicAdd(&cursor[s], 1);
    tvals[pos] = t;
    wv[pos] = expf(tanhf(ss[s] + ts[t] + ab_ptr[0]));
}

// ---------------- fused GAT aggregate + combine (bf16 rows) -----------------
// out[s,:] = (head[s,:] + (sum_j w_j T[t_j,:]) / (sum_j w_j) + gbias) * 0.5
// 4-wide unrolled gather: 4 independent row loads in flight.
__global__ __launch_bounds__(256)
void gat_agg_kernel(const int* __restrict__ offs, const int* __restrict__ tvals,
                    const float* __restrict__ wv, const short* __restrict__ T,
                    const short* __restrict__ head, const float* __restrict__ gbias,
                    short* __restrict__ out, int N)
{
    int s = blockIdx.x * 4 + (threadIdx.x >> 6);
    int lane = threadIdx.x & 63;
    if (s >= N) return;
    const int beg = offs[s], end = offs[s + 1];
    float a[8];
#pragma unroll
    for (int q = 0; q < 8; ++q) a[q] = 0.f;
    float den = 0.f;

    int j = beg;
    for (; j + 4 <= end; j += 4) {
        int t0 = tvals[j], t1 = tvals[j + 1], t2 = tvals[j + 2], t3 = tvals[j + 3];
        float w0 = wv[j], w1 = wv[j + 1], w2 = wv[j + 2], w3 = wv[j + 3];
        short8v v0 = ((const short8v*)(T + (size_t)t0 * HH))[lane];
        short8v v1 = ((const short8v*)(T + (size_t)t1 * HH))[lane];
        short8v v2 = ((const short8v*)(T + (size_t)t2 * HH))[lane];
        short8v v3 = ((const short8v*)(T + (size_t)t3 * HH))[lane];
        den += w0 + w1 + w2 + w3;
#pragma unroll
        for (int q = 0; q < 8; ++q) {
            float acc = a[q];
            acc = fmaf(w0, bf2f(v0[q]), acc);
            acc = fmaf(w1, bf2f(v1[q]), acc);
            acc = fmaf(w2, bf2f(v2[q]), acc);
            acc = fmaf(w3, bf2f(v3[q]), acc);
            a[q] = acc;
        }
    }
    for (; j < end; ++j) {
        int t = tvals[j];
        float w = wv[j];
        short8v tv = ((const short8v*)(T + (size_t)t * HH))[lane];
        den += w;
#pragma unroll
        for (int q = 0; q < 8; ++q) a[q] = fmaf(w, bf2f(tv[q]), a[q]);
    }
    float inv = (den > 0.f) ? 1.f / den : 0.f;

    short8v h = ((const short8v*)(head + (size_t)s * HH))[lane];
    const float4* bp = (const float4*)gbias + lane * 2;
    float4 b0 = bp[0], b1 = bp[1];
    float bb[8] = {b0.x, b0.y, b0.z, b0.w, b1.x, b1.y, b1.z, b1.w};
    short8v o;
#pragma unroll
    for (int q = 0; q < 8; ++q)
        o[q] = f2bf((bf2f(h[q]) + a[q] * inv + bb[q]) * 0.5f);
    ((short8v*)(out + (size_t)s * HH))[lane] = o;
}

// ---------------- out = LN(tanh(Z [+ res])) * g + b, row-wise (H=512) -------
// Z bf16; res fp32 (nullable); outB bf16 (nullable); outF fp32 (nullable);
// optional fused classifier: outCls[row] = sigmoid(out_row . cW + cb)
__global__ __launch_bounds__(256)
void tanh_ln_kernel(const short* __restrict__ Z, const float* __restrict__ res,
                    const float* __restrict__ g, const float* __restrict__ bta,
                    short* __restrict__ outB, float* __restrict__ outF,
                    const float* __restrict__ cWp, const float* __restrict__ cbp,
                    float* __restrict__ outCls, int N)
{
    int row = blockIdx.x * 4 + (threadIdx.x >> 6);
    int lane = threadIdx.x & 63;
    if (row >= N) return;
    short8v zv = ((const short8v*)(Z + (size_t)row * HH))[lane];
    float v[8];
    float sum = 0.f, sum2 = 0.f;
    float rr[8];
    if (res) {
        const float4* rp = (const float4*)(res + (size_t)row * HH) + lane * 2;
        float4 r0 = rp[0], r1 = rp[1];
        rr[0]=r0.x; rr[1]=r0.y; rr[2]=r0.z; rr[3]=r0.w;
        rr[4]=r1.x; rr[5]=r1.y; rr[6]=r1.z; rr[7]=r1.w;
    } else {
#pragma unroll
        for (int q = 0; q < 8; ++q) rr[q] = 0.f;
    }
#pragma unroll
    for (int q = 0; q < 8; ++q) {
        float t = tanhf(bf2f(zv[q]) + rr[q]);
        v[q] = t;
        sum += t;
        sum2 = fmaf(t, t, sum2);
    }
#pragma unroll
    for (int m = 32; m >= 1; m >>= 1) {
        sum  += __shfl_xor(sum, m);
        sum2 += __shfl_xor(sum2, m);
    }
    float mu  = sum * (1.f/HH);
    float var = sum2 * (1.f/HH) - mu*mu;
    float rs  = rsqrtf(var + 1e-5f);
    const float4* gp = (const float4*)g + lane * 2;
    const float4* bp = (const float4*)bta + lane * 2;
    float4 g0 = gp[0], g1 = gp[1], c0 = bp[0], c1 = bp[1];
    float gg[8] = {g0.x, g0.y, g0.z, g0.w, g1.x, g1.y, g1.z, g1.w};
    float cc[8] = {c0.x, c0.y, c0.z, c0.w, c1.x, c1.y, c1.z, c1.w};
    float o[8];
#pragma unroll
    for (int q = 0; q < 8; ++q) o[q] = (v[q]-mu)*rs*gg[q] + cc[q];
    if (outB) {
        short8v ob;
#pragma unroll
        for (int q = 0; q < 8; ++q) ob[q] = f2bf(o[q]);
        ((short8v*)(outB + (size_t)row * HH))[lane] = ob;
    }
    if (outF) {
        float4* op = (float4*)(outF + (size_t)row * HH) + lane * 2;
        op[0] = make_float4(o[0], o[1], o[2], o[3]);
        op[1] = make_float4(o[4], o[5], o[6], o[7]);
    }
    if (cWp) {
        const float4* wp = (const float4*)cWp + lane * 2;
        float4 w0 = wp[0], w1 = wp[1];
        float acc = o[0]*w0.x + o[1]*w0.y + o[2]*w0.z + o[3]*w0.w
                  + o[4]*w1.x + o[5]*w1.y + o[6]*w1.z + o[7]*w1.w;
#pragma unroll
        for (int m = 32; m >= 1; m >>= 1) acc += __shfl_xor(acc, m);
        if (lane == 0) outCls[row] = 1.f / (1.f + expf(-(acc + cbp[0])));
    }
}

extern "C" void kernel_launch(void* const* d_in, const int* in_sizes, int n_in,
                              void* d_out, int out_size, void* d_ws, size_t ws_size,
                              hipStream_t stream)
{
    (void)in_sizes; (void)n_in; (void)out_size; (void)ws_size;
    const int N = NN, E = NE, H = HH;
    const size_t NHf = (size_t)N * H;

    const float* fu0 = (const float*)d_in[0];
    const float* fi1 = (const float*)d_in[3];
    const float* fu2 = (const float*)d_in[4];
    const int* eUI0 = (const int*)d_in[6];
    const int* eIU1 = (const int*)d_in[9];
    const float* Wu  = (const float*)d_in[10];
    const float* bu  = (const float*)d_in[11];
    const float* Wi  = (const float*)d_in[12];
    const float* bi  = (const float*)d_in[13];
    const float* gfW = (const float*)d_in[14];
    const float* gfb = (const float*)d_in[15];
    const float* gaw = (const float*)d_in[16];
    const float* gab = (const float*)d_in[17];
    const float* gbias = (const float*)d_in[18];
    const float* prW = (const float*)d_in[19];
    const float* prb = (const float*)d_in[20];
    const float* dW  = (const float*)d_in[21];
    const float* db  = (const float*)d_in[22];
    const float* dlg = (const float*)d_in[23];
    const float* dlb = (const float*)d_in[24];
    const float* rlg = (const float*)d_in[25];
    const float* rlb = (const float*)d_in[26];
    const float* cW  = (const float*)d_in[27];
    const float* cb  = (const float*)d_in[28];

    // fp32 region
    float* B5   = (float*)d_ws;      // residual sc (fp32)
    float* ssb  = B5 + NHf;          // [N]
    float* tsb  = ssb + N;           // [N]
    float* uv   = tsb + N;           // [1024]
    float* s0t0 = uv + 1024;         // [2] (+pad)
    float* wvb  = s0t0 + 4;          // [E]
    int* counts0 = (int*)(wvb + E);  // [N]
    int* counts1 = counts0 + N;      // [N]
    int* offs0   = counts1 + N;      // [N+1]
    int* offs1   = offs0 + N + 1;    // [N+1]
    int* cur0    = offs1 + N + 1;    // [N]
    int* cur1    = cur0 + N;         // [N]
    int* tvals   = cur1 + N;         // [E]
    size_t boff = (size_t)((char*)(tvals + E) - (char*)d_ws);
    boff = (boff + 15) & ~(size_t)15;
    // bf16 activations (lifetime-based reuse)
    short* S0    = (short*)((char*)d_ws + boff); // [2*NHf]: fu2 bf16, fu0 bf16
    short* SUHU  = S0 + 2 * NHf;                 // [2*NHf]: su, hu0
    short* XI1   = SUHU + 2 * NHf;               // [NHf/2] raw item feat
    short* HI    = XI1 + NHf / 2;                // hi
    short* SINEW = HI + NHf;                     // si_new ; later XB
    short* T4    = SINEW + NHf;                  // gat tail transform
    short* SUF   = T4 + NHf;                     // su_final
    short* WTu   = SUF + NHf;
    short* WTi   = WTu + 512 * 512;
    short* WTg0  = WTi + 512 * 256;
    short* WTg1  = WTg0 + 512 * 512;
    short* WTpr  = WTg1 + 512 * 512;
    short* WTd   = WTpr + 512 * 512;             // 4 x 512*512
    short* SU  = SUHU;
    short* HU0 = SUHU + NHf;
    short* XB  = SINEW;   // alias after GAT0 done
    short* ZB  = SU;      // alias after both GATs done (SUHU free)

    // ---- weight pre-pass ----
    auto WTR = [&](const float* src, short* dst, int K) {
        hipLaunchKernelGGL(wtr_kernel, dim3(16, K / 32), dim3(32, 8), 0, stream,
                           src, dst, K, 512);
    };
    WTR(Wu, WTu, 512);
    WTR(Wi, WTi, 256);
    WTR(gfW, WTg0, 512);
    WTR(gfW + (size_t)H * H, WTg1, 512);
    WTR(prW, WTpr, 512);
    for (int k = 0; k < 4; ++k)
        WTR(dW + (size_t)k * H * H, WTd + (size_t)k * 512 * 512, 512);

    auto F2B = [&](const float* src, short* dst, size_t n) {
        int n8 = (int)(n / 8);
        hipLaunchKernelGGL(f2b_kernel, dim3((n8 + 255) / 256), dim3(256), 0, stream,
                           src, dst, n8);
    };

    // ---- CSR build ----
    hipMemsetAsync(counts0, 0, 2 * N * sizeof(int), stream);
    hipLaunchKernelGGL(count2_kernel, dim3((2 * E + 255) / 256), dim3(256), 0, stream,
                       eUI0, eIU1, counts0, counts1, E);
    hipLaunchKernelGGL(scan2_kernel, dim3(2), dim3(1024), 0, stream,
                       counts0, counts1, offs0, offs1, cur0, cur1, N);

    auto MLIN = [&](const short* X, const short* WT, const float* b,
                    float* oF, short* oB, int M, int K) {
        int nwg = ((M + 127) / 128) * 4;
        hipLaunchKernelGGL(mfma_lin, dim3(nwg), dim3(256), 0, stream,
                           X, WT, b, oF, oB, M, K);
    };
    const int rgrid = (N + 3) / 4;
    const int egrid = (E + 255) / 256;

    auto GAT = [&](int r, const short* headB, const short* tailB, const short* WTg,
                   const int* edges, int* offs, int* curs, short* outB) {
        hipLaunchKernelGGL(gat_pre_kernel, dim3(130), dim3(256), 0, stream,
                           gfW + (size_t)r * H * H, gfb + r * H, gaw + (size_t)r * 2 * H,
                           uv, s0t0);
        MLIN(tailB, WTg, gfb + r * H, nullptr, T4, N, 512);
        hipLaunchKernelGGL(rowdot2_kernel, dim3(rgrid), dim3(256), 0, stream,
                           headB, tailB, uv, s0t0, ssb, tsb, N);
        hipLaunchKernelGGL(fill_kernel, dim3(egrid), dim3(256), 0, stream,
                           edges, edges + E, ssb, tsb, gab + r, curs, tvals, wvb, E);
        hipLaunchKernelGGL(gat_agg_kernel, dim3(rgrid), dim3(256), 0, stream,
                           offs, tvals, wvb, T4, headB, gbias + (size_t)r * H, outB, N);
    };

    // input transforms (su & hu0 batched: M = 2N over contiguous S0 -> SUHU)
    F2B(fu2, S0, NHf);
    F2B(fu0, S0 + NHf, NHf);
    F2B(fi1, XI1, NHf / 2);
    MLIN(S0, WTu, bu, nullptr, SUHU, 2 * N, 512);     // su + hu0
    MLIN(XI1, WTi, bi, nullptr, HI, N, 256);          // hi
    GAT(1, HI, SU, WTg1, eIU1, offs1, cur1, SINEW);   // si_new
    GAT(0, HU0, SINEW, WTg0, eUI0, offs0, cur0, SUF); // su_final

    // Res_DNN head (classic split: MLIN + tanh_ln; prep dual-writes sc fp32)
    MLIN(SUF, WTpr, prb, B5, XB, N, 512);
    for (int r = 0; r < 2; ++r) {
        for (int d = 0; d < 2; ++d) {
            MLIN(XB, WTd + (size_t)(r * 2 + d) * 512 * 512, db + (r * 2 + d) * H,
                 nullptr, ZB, N, 512);
            hipLaunchKernelGGL(tanh_ln_kernel, dim3(rgrid), dim3(256), 0, stream,
                               ZB, (const float*)nullptr, dlg + (r * 2 + d) * H,
                               dlb + (r * 2 + d) * H, XB, (float*)nullptr,
                               (const float*)nullptr, (const float*)nullptr,
                               (float*)nullptr, N);
        }
        if (r == 0) {
            hipLaunchKernelGGL(tanh_ln_kernel, dim3(rgrid), dim3(256), 0, stream,
                               XB, B5, rlg, rlb, XB, B5,
                               (const float*)nullptr, (const float*)nullptr,
                               (float*)nullptr, N);
        } else {
            hipLaunchKernelGGL(tanh_ln_kernel, dim3(rgrid), dim3(256), 0, stream,
                               XB, B5, rlg + H, rlb + H, (short*)nullptr,
                               (float*)nullptr, cW, cb, (float*)d_out, N);
        }
    }
}

// Round 8
// 571.746 us; speedup vs baseline: 1.2589x; 1.0260x over previous
//
#include <hip/hip_runtime.h>
#include <math.h>

#define NN 20000
#define NE 200000
#define HH 512

typedef __attribute__((ext_vector_type(8))) short short8v;
typedef __attribute__((ext_vector_type(4))) float f32x4;

__device__ inline short f2bf(float f) {
    union { float f; unsigned u; } v; v.f = f;
    unsigned r = (v.u + 0x7fffu + ((v.u >> 16) & 1u)) >> 16;
    return (short)r;
}
__device__ inline float bf2f(short s) {
    union { unsigned u; float f; } v;
    v.u = ((unsigned)(unsigned short)s) << 16;
    return v.f;
}

// direct global->LDS DMA, 16B per lane; lds dest must be wave-uniform base
__device__ inline void gload_lds16(const void* g, void* l) {
    __builtin_amdgcn_global_load_lds(
        (const __attribute__((address_space(1))) void*)g,
        (__attribute__((address_space(3))) void*)l, 16, 0, 0);
}

// ---------------- fp32 -> bf16 bulk convert (8 elems/thread) ----------------
__global__ __launch_bounds__(256)
void f2b_kernel(const float* __restrict__ src, short* __restrict__ dst, int n8)
{
    int i = blockIdx.x * 256 + threadIdx.x;
    if (i >= n8) return;
    const float4* p = (const float4*)src + (size_t)i * 2;
    float4 a = p[0], b = p[1];
    short8v s;
    s[0] = f2bf(a.x); s[1] = f2bf(a.y); s[2] = f2bf(a.z); s[3] = f2bf(a.w);
    s[4] = f2bf(b.x); s[5] = f2bf(b.y); s[6] = f2bf(b.z); s[7] = f2bf(b.w);
    ((short8v*)dst)[i] = s;
}

// ---------------- weight transpose + bf16 convert: dst[n][k] = src[k][n] ----
__global__ __launch_bounds__(256)
void wtr_kernel(const float* __restrict__ src, short* __restrict__ dst,
                int K, int Ncols)
{
    __shared__ float t[32][33];
    int bx = blockIdx.x * 32;
    int by = blockIdx.y * 32;
    int tx = threadIdx.x, ty = threadIdx.y;
    for (int i = ty; i < 32; i += 8)
        t[i][tx] = src[(size_t)(by + i) * Ncols + bx + tx];
    __syncthreads();
    for (int i = ty; i < 32; i += 8)
        dst[(size_t)(bx + i) * K + by + tx] = f2bf(t[tx][i]);
}

// ---------------- MFMA GEMM: out[M,512] = X[M,K](bf16) @ WT[512,K](bf16)^T + b
// 128x128 tile, BK=32, 4 waves (2x2), wave 64x64 (4x4 frags of 16x16x32).
// 3-deep global_load_lds pipeline with counted vmcnt (never drains to 0 in
// the main loop); coalesced bf16 epilogue via wave-private LDS transpose.
__global__ __launch_bounds__(256)
void mfma_lin(const short* __restrict__ X, const short* __restrict__ WT,
              const float* __restrict__ bias, float* __restrict__ outF,
              short* __restrict__ outB, int M, int K)
{
    // pool: A bufs = pool[buf*512 .. +512), B bufs = pool[1536 + buf*512 ..)
    __shared__ short8v pool[3072];   // 48 KB

    const int tid = threadIdx.x;
    const int lane = tid & 63;
    const int w = tid >> 6;

    const int nby = (M + 127) >> 7;
    const int nwg = nby << 2;
    const int q = nwg >> 3, r = nwg & 7;
    int id = blockIdx.x;
    int xcd = id & 7, wi = id >> 3;
    int wgid = (xcd < r ? xcd * (q + 1) : r * (q + 1) + (xcd - r) * q) + wi;
    const int col0 = (wgid & 3) * 128;
    const int row0 = (wgid >> 2) * 128;

    const int wr = (w >> 1) * 64;
    const int wc = (w & 1) * 64;

    int sp0 = w * 128 + lane;
    int sp1 = sp0 + 64;
    int r0_ = sp0 >> 2, r1_ = sp1 >> 2;
    int c0_ = (sp0 & 3) ^ ((r0_ >> 1) & 3);
    int c1_ = (sp1 & 3) ^ ((r1_ >> 1) & 3);
    int ga0 = row0 + r0_; if (ga0 >= M) ga0 = M - 1;
    int ga1 = row0 + r1_; if (ga1 >= M) ga1 = M - 1;
    const short* ag0 = X + (size_t)ga0 * K + c0_ * 8;
    const short* ag1 = X + (size_t)ga1 * K + c1_ * 8;
    const short* bg0 = WT + (size_t)(col0 + r0_) * K + c0_ * 8;
    const short* bg1 = WT + (size_t)(col0 + r1_) * K + c1_ * 8;

    int ar[4], br[4];
#pragma unroll
    for (int i = 0; i < 4; ++i) {
        int rr = wr + i * 16 + (lane & 15);
        ar[i] = rr * 4 + ((lane >> 4) ^ ((rr >> 1) & 3));
        int nn = wc + i * 16 + (lane & 15);
        br[i] = nn * 4 + ((lane >> 4) ^ ((nn >> 1) & 3));
    }

    f32x4 acc[4][4];
#pragma unroll
    for (int i = 0; i < 4; ++i)
#pragma unroll
        for (int j = 0; j < 4; ++j)
            acc[i][j] = (f32x4){0.f, 0.f, 0.f, 0.f};

    auto stage = [&](int buf, int kk) {
        short8v* A = pool + buf * 512;
        short8v* B = pool + 1536 + buf * 512;
        gload_lds16(ag0 + kk, A + w * 128);
        gload_lds16(ag1 + kk, A + w * 128 + 64);
        gload_lds16(bg0 + kk, B + w * 128);
        gload_lds16(bg1 + kk, B + w * 128 + 64);
    };

    const int nt = K >> 5;            // 8 or 16
    stage(0, 0);
    if (nt > 1) stage(1, 32);
    if (nt > 2) stage(2, 64);
    int cur = 0;
    for (int t = 0; t < nt; ++t) {
        // wait for stage t only; keep up to 2 younger stages (8 loads) in flight
        if (t + 2 < nt)      asm volatile("s_waitcnt vmcnt(8)" ::: "memory");
        else if (t + 1 < nt) asm volatile("s_waitcnt vmcnt(4)" ::: "memory");
        else                 asm volatile("s_waitcnt vmcnt(0)" ::: "memory");
        __builtin_amdgcn_s_barrier();
        const short8v* A = pool + cur * 512;
        const short8v* B = pool + 1536 + cur * 512;
        short8v af[4], bf[4];
#pragma unroll
        for (int i = 0; i < 4; ++i) af[i] = A[ar[i]];
#pragma unroll
        for (int j = 0; j < 4; ++j) bf[j] = B[br[j]];
#pragma unroll
        for (int i = 0; i < 4; ++i)
#pragma unroll
            for (int j = 0; j < 4; ++j)
                acc[i][j] = __builtin_amdgcn_mfma_f32_16x16x32_bf16(af[i], bf[j], acc[i][j], 0, 0, 0);
        __builtin_amdgcn_s_barrier();          // all waves done reading buf cur
        if (t + 3 < nt) stage(cur, (t + 3) * 32);
        cur = (cur == 2) ? 0 : cur + 1;
    }

    float bj[4];
#pragma unroll
    for (int j = 0; j < 4; ++j)
        bj[j] = bias[col0 + wc + j * 16 + (lane & 15)];

    if (outF) {   // fp32 path (prep's residual copy only) — scalar stores
#pragma unroll
        for (int i = 0; i < 4; ++i) {
#pragma unroll
            for (int rr = 0; rr < 4; ++rr) {
                int row = row0 + wr + i * 16 + (lane >> 4) * 4 + rr;
                if (row < M) {
                    float* op = outF + (size_t)row * HH + col0 + wc + (lane & 15);
#pragma unroll
                    for (int j = 0; j < 4; ++j) op[j * 16] = acc[i][j][rr] + bj[j];
                }
            }
        }
    }
    if (outB) {   // bf16 path: wave-private LDS transpose -> coalesced short8
        short* lds = (short*)pool + w * 4608;   // 64 rows x 72 shorts (9216 B/wave)
#pragma unroll
        for (int i = 0; i < 4; ++i)
#pragma unroll
            for (int rr = 0; rr < 4; ++rr) {
                int lrow = i * 16 + (lane >> 4) * 4 + rr;
#pragma unroll
                for (int j = 0; j < 4; ++j)
                    lds[lrow * 72 + j * 16 + (lane & 15)] = f2bf(acc[i][j][rr] + bj[j]);
            }
        // intra-wave dependency only (each wave reads its own region)
#pragma unroll
        for (int k = 0; k < 8; ++k) {
            int lr = (lane >> 3) + 8 * k;
            int lc = (lane & 7) * 8;
            int grow = row0 + wr + lr;
            if (grow < M) {
                short8v vv = *(short8v*)(lds + lr * 72 + lc);
                *(short8v*)(outB + (size_t)grow * HH + col0 + wc + lc) = vv;
            }
        }
    }
}

// ---------------- gat_pre: u = fW @ aw[:512], v = fW @ aw[512:], fb dots -----
__global__ __launch_bounds__(256)
void gat_pre_kernel(const float* __restrict__ fW, const float* __restrict__ fb,
                    const float* __restrict__ aw, float* __restrict__ uv,
                    float* __restrict__ s0t0)
{
    int row = blockIdx.x * 4 + (threadIdx.x >> 6);
    int lane = threadIdx.x & 63;
    const float4* ah = (const float4*)aw;
    const float4* at = (const float4*)(aw + HH);
    const float4* fp;
    if (row < 512)      fp = (const float4*)(fW + (size_t)row * HH);
    else if (row == 512) fp = (const float4*)fb;
    else return;
    float du = 0.f, dv = 0.f;
#pragma unroll
    for (int l = 0; l < 2; ++l) {
        int idx = lane * 2 + l;
        float4 f = fp[idx], a = ah[idx], b = at[idx];
        du += f.x*a.x + f.y*a.y + f.z*a.z + f.w*a.w;
        dv += f.x*b.x + f.y*b.y + f.z*b.z + f.w*b.w;
    }
#pragma unroll
    for (int m = 32; m >= 1; m >>= 1) {
        du += __shfl_xor(du, m);
        dv += __shfl_xor(dv, m);
    }
    if (lane == 0) {
        if (row < 512) { uv[row] = du; uv[512 + row] = dv; }
        else           { s0t0[0] = du; s0t0[1] = dv; }
    }
}

// ---------------- rowdot2: ss[n]=Head[n].u+s0, ts[n]=Tail[n].v+t0 (bf16 rows)
__global__ __launch_bounds__(256)
void rowdot2_kernel(const short* __restrict__ Hd, const short* __restrict__ Tl,
                    const float* __restrict__ uv, const float* __restrict__ s0t0,
                    float* __restrict__ ss, float* __restrict__ ts, int N)
{
    int row = blockIdx.x * 4 + (threadIdx.x >> 6);
    int lane = threadIdx.x & 63;
    if (row >= N) return;
    short8v h = ((const short8v*)(Hd + (size_t)row * HH))[lane];
    short8v t = ((const short8v*)(Tl + (size_t)row * HH))[lane];
    const float4* up = (const float4*)uv + lane * 2;
    const float4* vp = (const float4*)(uv + HH) + lane * 2;
    float4 u0 = up[0], u1 = up[1], v0 = vp[0], v1 = vp[1];
    float a = bf2f(h[0])*u0.x + bf2f(h[1])*u0.y + bf2f(h[2])*u0.z + bf2f(h[3])*u0.w
            + bf2f(h[4])*u1.x + bf2f(h[5])*u1.y + bf2f(h[6])*u1.z + bf2f(h[7])*u1.w;
    float b = bf2f(t[0])*v0.x + bf2f(t[1])*v0.y + bf2f(t[2])*v0.z + bf2f(t[3])*v0.w
            + bf2f(t[4])*v1.x + bf2f(t[5])*v1.y + bf2f(t[6])*v1.z + bf2f(t[7])*v1.w;
#pragma unroll
    for (int m = 32; m >= 1; m >>= 1) {
        a += __shfl_xor(a, m);
        b += __shfl_xor(b, m);
    }
    if (lane == 0) { ss[row] = a + s0t0[0]; ts[row] = b + s0t0[1]; }
}

// ---------------- CSR build (both relations, hoisted) ----------------
__global__ __launch_bounds__(256)
void count2_kernel(const int* __restrict__ s0, const int* __restrict__ s1,
                   int* __restrict__ c0, int* __restrict__ c1, int E)
{
    int i = blockIdx.x * blockDim.x + threadIdx.x;
    if (i < E) atomicAdd(&c0[s0[i]], 1);
    else if (i < 2 * E) atomicAdd(&c1[s1[i - E]], 1);
}

__global__ __launch_bounds__(1024)
void scan2_kernel(const int* __restrict__ c0, const int* __restrict__ c1,
                  int* __restrict__ o0, int* __restrict__ o1,
                  int* __restrict__ u0, int* __restrict__ u1, int n)
{
    const int* counts = blockIdx.x ? c1 : c0;
    int* offs = blockIdx.x ? o1 : o0;
    int* curs = blockIdx.x ? u1 : u0;
    __shared__ int part[1024];
    const int tid = threadIdx.x;
    const int CH = (n + 1023) / 1024;
    const int base = tid * CH;
    int s = 0;
    for (int i = 0; i < CH; ++i) {
        int idx = base + i;
        if (idx < n) s += counts[idx];
    }
    part[tid] = s;
    __syncthreads();
    for (int d = 1; d < 1024; d <<= 1) {
        int v = 0;
        if (tid >= d) v = part[tid - d];
        __syncthreads();
        if (tid >= d) part[tid] += v;
        __syncthreads();
    }
    int run = (tid == 0) ? 0 : part[tid - 1];
    for (int i = 0; i < CH; ++i) {
        int idx = base + i;
        if (idx < n) { offs[idx] = run; curs[idx] = run; run += counts[idx]; }
    }
    if (tid == 1023) offs[n] = run;
}

// fill CSR with target ids AND precomputed edge weights
__global__ __launch_bounds__(256)
void fill_kernel(const int* __restrict__ src, const int* __restrict__ tgt,
                 const float* __restrict__ ss, const float* __restrict__ ts,
                 const float* __restrict__ ab_ptr, int* __restrict__ cursor,
                 int* __restrict__ tvals, float* __restrict__ wv, int E)
{
    int i = blockIdx.x * blockDim.x + threadIdx.x;
    if (i >= E) return;
    int s = src[i], t = tgt[i];
    int pos = atomicAdd(&cursor[s], 1);
    tvals[pos] = t;
    wv[pos] = expf(tanhf(ss[s] + ts[t] + ab_ptr[0]));
}

// ---------------- fused GAT aggregate + combine (bf16 rows) -----------------
// out[s,:] = (head[s,:] + (sum_j w_j T[t_j,:]) / (sum_j w_j) + gbias) * 0.5
__global__ __launch_bounds__(256)
void gat_agg_kernel(const int* __restrict__ offs, const int* __restrict__ tvals,
                    const float* __restrict__ wv, const short* __restrict__ T,
                    const short* __restrict__ head, const float* __restrict__ gbias,
                    short* __restrict__ out, int N)
{
    int s = blockIdx.x * 4 + (threadIdx.x >> 6);
    int lane = threadIdx.x & 63;
    if (s >= N) return;
    const int beg = offs[s], end = offs[s + 1];
    float a[8];
#pragma unroll
    for (int q = 0; q < 8; ++q) a[q] = 0.f;
    float den = 0.f;

    int j = beg;
    for (; j + 4 <= end; j += 4) {
        int t0 = tvals[j], t1 = tvals[j + 1], t2 = tvals[j + 2], t3 = tvals[j + 3];
        float w0 = wv[j], w1 = wv[j + 1], w2 = wv[j + 2], w3 = wv[j + 3];
        short8v v0 = ((const short8v*)(T + (size_t)t0 * HH))[lane];
        short8v v1 = ((const short8v*)(T + (size_t)t1 * HH))[lane];
        short8v v2 = ((const short8v*)(T + (size_t)t2 * HH))[lane];
        short8v v3 = ((const short8v*)(T + (size_t)t3 * HH))[lane];
        den += w0 + w1 + w2 + w3;
#pragma unroll
        for (int q = 0; q < 8; ++q) {
            float acc = a[q];
            acc = fmaf(w0, bf2f(v0[q]), acc);
            acc = fmaf(w1, bf2f(v1[q]), acc);
            acc = fmaf(w2, bf2f(v2[q]), acc);
            acc = fmaf(w3, bf2f(v3[q]), acc);
            a[q] = acc;
        }
    }
    for (; j < end; ++j) {
        int t = tvals[j];
        float w = wv[j];
        short8v tv = ((const short8v*)(T + (size_t)t * HH))[lane];
        den += w;
#pragma unroll
        for (int q = 0; q < 8; ++q) a[q] = fmaf(w, bf2f(tv[q]), a[q]);
    }
    float inv = (den > 0.f) ? 1.f / den : 0.f;

    short8v h = ((const short8v*)(head + (size_t)s * HH))[lane];
    const float4* bp = (const float4*)gbias + lane * 2;
    float4 b0 = bp[0], b1 = bp[1];
    float bb[8] = {b0.x, b0.y, b0.z, b0.w, b1.x, b1.y, b1.z, b1.w};
    short8v o;
#pragma unroll
    for (int q = 0; q < 8; ++q)
        o[q] = f2bf((bf2f(h[q]) + a[q] * inv + bb[q]) * 0.5f);
    ((short8v*)(out + (size_t)s * HH))[lane] = o;
}

// ---------------- out = LN(tanh(Z [+ res])) * g + b, row-wise (H=512) -------
__global__ __launch_bounds__(256)
void tanh_ln_kernel(const short* __restrict__ Z, const float* __restrict__ res,
                    const float* __restrict__ g, const float* __restrict__ bta,
                    short* __restrict__ outB, float* __restrict__ outF,
                    const float* __restrict__ cWp, const float* __restrict__ cbp,
                    float* __restrict__ outCls, int N)
{
    int row = blockIdx.x * 4 + (threadIdx.x >> 6);
    int lane = threadIdx.x & 63;
    if (row >= N) return;
    short8v zv = ((const short8v*)(Z + (size_t)row * HH))[lane];
    float v[8];
    float sum = 0.f, sum2 = 0.f;
    float rr[8];
    if (res) {
        const float4* rp = (const float4*)(res + (size_t)row * HH) + lane * 2;
        float4 r0 = rp[0], r1 = rp[1];
        rr[0]=r0.x; rr[1]=r0.y; rr[2]=r0.z; rr[3]=r0.w;
        rr[4]=r1.x; rr[5]=r1.y; rr[6]=r1.z; rr[7]=r1.w;
    } else {
#pragma unroll
        for (int q = 0; q < 8; ++q) rr[q] = 0.f;
    }
#pragma unroll
    for (int q = 0; q < 8; ++q) {
        float t = tanhf(bf2f(zv[q]) + rr[q]);
        v[q] = t;
        sum += t;
        sum2 = fmaf(t, t, sum2);
    }
#pragma unroll
    for (int m = 32; m >= 1; m >>= 1) {
        sum  += __shfl_xor(sum, m);
        sum2 += __shfl_xor(sum2, m);
    }
    float mu  = sum * (1.f/HH);
    float var = sum2 * (1.f/HH) - mu*mu;
    float rs  = rsqrtf(var + 1e-5f);
    const float4* gp = (const float4*)g + lane * 2;
    const float4* bp = (const float4*)bta + lane * 2;
    float4 g0 = gp[0], g1 = gp[1], c0 = bp[0], c1 = bp[1];
    float gg[8] = {g0.x, g0.y, g0.z, g0.w, g1.x, g1.y, g1.z, g1.w};
    float cc[8] = {c0.x, c0.y, c0.z, c0.w, c1.x, c1.y, c1.z, c1.w};
    float o[8];
#pragma unroll
    for (int q = 0; q < 8; ++q) o[q] = (v[q]-mu)*rs*gg[q] + cc[q];
    if (outB) {
        short8v ob;
#pragma unroll
        for (int q = 0; q < 8; ++q) ob[q] = f2bf(o[q]);
        ((short8v*)(outB + (size_t)row * HH))[lane] = ob;
    }
    if (outF) {
        float4* op = (float4*)(outF + (size_t)row * HH) + lane * 2;
        op[0] = make_float4(o[0], o[1], o[2], o[3]);
        op[1] = make_float4(o[4], o[5], o[6], o[7]);
    }
    if (cWp) {
        const float4* wp = (const float4*)cWp + lane * 2;
        float4 w0 = wp[0], w1 = wp[1];
        float acc = o[0]*w0.x + o[1]*w0.y + o[2]*w0.z + o[3]*w0.w
                  + o[4]*w1.x + o[5]*w1.y + o[6]*w1.z + o[7]*w1.w;
#pragma unroll
        for (int m = 32; m >= 1; m >>= 1) acc += __shfl_xor(acc, m);
        if (lane == 0) outCls[row] = 1.f / (1.f + expf(-(acc + cbp[0])));
    }
}

extern "C" void kernel_launch(void* const* d_in, const int* in_sizes, int n_in,
                              void* d_out, int out_size, void* d_ws, size_t ws_size,
                              hipStream_t stream)
{
    (void)in_sizes; (void)n_in; (void)out_size; (void)ws_size;
    const int N = NN, E = NE, H = HH;
    const size_t NHf = (size_t)N * H;

    const float* fu0 = (const float*)d_in[0];
    const float* fi1 = (const float*)d_in[3];
    const float* fu2 = (const float*)d_in[4];
    const int* eUI0 = (const int*)d_in[6];
    const int* eIU1 = (const int*)d_in[9];
    const float* Wu  = (const float*)d_in[10];
    const float* bu  = (const float*)d_in[11];
    const float* Wi  = (const float*)d_in[12];
    const float* bi  = (const float*)d_in[13];
    const float* gfW = (const float*)d_in[14];
    const float* gfb = (const float*)d_in[15];
    const float* gaw = (const float*)d_in[16];
    const float* gab = (const float*)d_in[17];
    const float* gbias = (const float*)d_in[18];
    const float* prW = (const float*)d_in[19];
    const float* prb = (const float*)d_in[20];
    const float* dW  = (const float*)d_in[21];
    const float* db  = (const float*)d_in[22];
    const float* dlg = (const float*)d_in[23];
    const float* dlb = (const float*)d_in[24];
    const float* rlg = (const float*)d_in[25];
    const float* rlb = (const float*)d_in[26];
    const float* cW  = (const float*)d_in[27];
    const float* cb  = (const float*)d_in[28];

    // fp32 region
    float* B5   = (float*)d_ws;      // residual sc (fp32)
    float* ssb  = B5 + NHf;          // [N]
    float* tsb  = ssb + N;           // [N]
    float* uv   = tsb + N;           // [1024]
    float* s0t0 = uv + 1024;         // [2] (+pad)
    float* wvb  = s0t0 + 4;          // [E]
    int* counts0 = (int*)(wvb + E);  // [N]
    int* counts1 = counts0 + N;      // [N]
    int* offs0   = counts1 + N;      // [N+1]
    int* offs1   = offs0 + N + 1;    // [N+1]
    int* cur0    = offs1 + N + 1;    // [N]
    int* cur1    = cur0 + N;         // [N]
    int* tvals   = cur1 + N;         // [E]
    size_t boff = (size_t)((char*)(tvals + E) - (char*)d_ws);
    boff = (boff + 15) & ~(size_t)15;
    // bf16 activations (lifetime-based reuse)
    short* S0    = (short*)((char*)d_ws + boff); // [2*NHf]: fu2 bf16, fu0 bf16
    short* SUHU  = S0 + 2 * NHf;                 // [2*NHf]: su, hu0
    short* XI1   = SUHU + 2 * NHf;               // [NHf/2] raw item feat
    short* HI    = XI1 + NHf / 2;                // hi
    short* SINEW = HI + NHf;                     // si_new ; later XB
    short* T4    = SINEW + NHf;                  // gat tail transform
    short* SUF   = T4 + NHf;                     // su_final
    short* WTu   = SUF + NHf;
    short* WTi   = WTu + 512 * 512;
    short* WTg0  = WTi + 512 * 256;
    short* WTg1  = WTg0 + 512 * 512;
    short* WTpr  = WTg1 + 512 * 512;
    short* WTd   = WTpr + 512 * 512;             // 4 x 512*512
    short* SU  = SUHU;
    short* HU0 = SUHU + NHf;
    short* XB  = SINEW;   // alias after GAT0 done
    short* ZB  = SU;      // alias after both GATs done (SUHU free)

    // ---- weight pre-pass ----
    auto WTR = [&](const float* src, short* dst, int K) {
        hipLaunchKernelGGL(wtr_kernel, dim3(16, K / 32), dim3(32, 8), 0, stream,
                           src, dst, K, 512);
    };
    WTR(Wu, WTu, 512);
    WTR(Wi, WTi, 256);
    WTR(gfW, WTg0, 512);
    WTR(gfW + (size_t)H * H, WTg1, 512);
    WTR(prW, WTpr, 512);
    for (int k = 0; k < 4; ++k)
        WTR(dW + (size_t)k * H * H, WTd + (size_t)k * 512 * 512, 512);

    auto F2B = [&](const float* src, short* dst, size_t n) {
        int n8 = (int)(n / 8);
        hipLaunchKernelGGL(f2b_kernel, dim3((n8 + 255) / 256), dim3(256), 0, stream,
                           src, dst, n8);
    };

    // ---- CSR build ----
    hipMemsetAsync(counts0, 0, 2 * N * sizeof(int), stream);
    hipLaunchKernelGGL(count2_kernel, dim3((2 * E + 255) / 256), dim3(256), 0, stream,
                       eUI0, eIU1, counts0, counts1, E);
    hipLaunchKernelGGL(scan2_kernel, dim3(2), dim3(1024), 0, stream,
                       counts0, counts1, offs0, offs1, cur0, cur1, N);

    auto MLIN = [&](const short* X, const short* WT, const float* b,
                    float* oF, short* oB, int M, int K) {
        int nwg = ((M + 127) / 128) * 4;
        hipLaunchKernelGGL(mfma_lin, dim3(nwg), dim3(256), 0, stream,
                           X, WT, b, oF, oB, M, K);
    };
    const int rgrid = (N + 3) / 4;
    const int egrid = (E + 255) / 256;

    auto GAT = [&](int r, const short* headB, const short* tailB, const short* WTg,
                   const int* edges, int* offs, int* curs, short* outB) {
        hipLaunchKernelGGL(gat_pre_kernel, dim3(130), dim3(256), 0, stream,
                           gfW + (size_t)r * H * H, gfb + r * H, gaw + (size_t)r * 2 * H,
                           uv, s0t0);
        MLIN(tailB, WTg, gfb + r * H, nullptr, T4, N, 512);
        hipLaunchKernelGGL(rowdot2_kernel, dim3(rgrid), dim3(256), 0, stream,
                           headB, tailB, uv, s0t0, ssb, tsb, N);
        hipLaunchKernelGGL(fill_kernel, dim3(egrid), dim3(256), 0, stream,
                           edges, edges + E, ssb, tsb, gab + r, curs, tvals, wvb, E);
        hipLaunchKernelGGL(gat_agg_kernel, dim3(rgrid), dim3(256), 0, stream,
                           offs, tvals, wvb, T4, headB, gbias + (size_t)r * H, outB, N);
    };

    // input transforms (su & hu0 batched: M = 2N over contiguous S0 -> SUHU)
    F2B(fu2, S0, NHf);
    F2B(fu0, S0 + NHf, NHf);
    F2B(fi1, XI1, NHf / 2);
    MLIN(S0, WTu, bu, nullptr, SUHU, 2 * N, 512);     // su + hu0
    MLIN(XI1, WTi, bi, nullptr, HI, N, 256);          // hi
    GAT(1, HI, SU, WTg1, eIU1, offs1, cur1, SINEW);   // si_new
    GAT(0, HU0, SINEW, WTg0, eUI0, offs0, cur0, SUF); // su_final

    // Res_DNN head (MLIN + tanh_ln; prep dual-writes sc fp32)
    MLIN(SUF, WTpr, prb, B5, XB, N, 512);
    for (int r = 0; r < 2; ++r) {
        for (int d = 0; d < 2; ++d) {
            MLIN(XB, WTd + (size_t)(r * 2 + d) * 512 * 512, db + (r * 2 + d) * H,
                 nullptr, ZB, N, 512);
            hipLaunchKernelGGL(tanh_ln_kernel, dim3(rgrid), dim3(256), 0, stream,
                               ZB, (const float*)nullptr, dlg + (r * 2 + d) * H,
                               dlb + (r * 2 + d) * H, XB, (float*)nullptr,
                               (const float*)nullptr, (const float*)nullptr,
                               (float*)nullptr, N);
        }
        if (r == 0) {
            hipLaunchKernelGGL(tanh_ln_kernel, dim3(rgrid), dim3(256), 0, stream,
                               XB, B5, rlg, rlb, XB, B5,
                               (const float*)nullptr, (const float*)nullptr,
                               (float*)nullptr, N);
        } else {
            hipLaunchKernelGGL(tanh_ln_kernel, dim3(rgrid), dim3(256), 0, stream,
                               XB, B5, rlg + H, rlb + H, (short*)nullptr,
                               (float*)nullptr, cW, cb, (float*)d_out, N);
        }
    }
}